// Round 24
// baseline (203.943 us; speedup 1.0000x reference)
//
#include <hip/hip_runtime.h>
#include <stdint.h>

// Problem constants
#define NSITES 784          // 4 * 196
#define LSZ    196          // 14*14
#define HWD    14
#define KKA_   288
#define BD_    512
#define NRG    8            // row-groups (288/36) — one per XCD
#define ROWS_PER_BLK 36
#define NW     6            // waves per block (384 thr)
#define ROWS_PER_WAVE 6     // 36 / 6 waves
#define SITES_PER_BLK 4
#define KC     8            // gemm1 K-split chunks (288 uint4 / 36)

// workspace layout (bytes)
#define WH_OFF    0            // W fp16 transposed (sweeps): 2,359,296
#define XH_OFF    2359296      // x fp16 [site][kk][c]:       3,612,672
#define WG_OFF    5971968      // W fp16 [kk][p][c] (gemm B): 2,359,296
#define GP_OFF    8331264      // gemm partials: 8*784*512*4 = 12,845,056
#define PART_OFF  21176320     // sweep partial: 784*8*512*4 = 12,845,056
#define VBUF_OFF  34021376     // v: 784*512*4               = 1,605,632
#define WS_NEED   35627008

typedef _Float16 h2 __attribute__((ext_vector_type(2)));
typedef _Float16 h8 __attribute__((ext_vector_type(8)));
typedef float    f4 __attribute__((ext_vector_type(4)));

// keep 8 floats pinned in VGPRs
#define PIN8(p) asm volatile("" : "+v"(p[0]),"+v"(p[1]),"+v"(p[2]),"+v"(p[3]), \
                                  "+v"(p[4]),"+v"(p[5]),"+v"(p[6]),"+v"(p[7]))

// 8-term fp16 dot with fp32 accumulate
__device__ __forceinline__ float dot8(const uint4 wv, const uint4 xv) {
    h2 w0 = __builtin_bit_cast(h2, wv.x), w1 = __builtin_bit_cast(h2, wv.y),
       w2 = __builtin_bit_cast(h2, wv.z), w3 = __builtin_bit_cast(h2, wv.w);
    h2 x0 = __builtin_bit_cast(h2, xv.x), x1 = __builtin_bit_cast(h2, xv.y),
       x2 = __builtin_bit_cast(h2, xv.z), x3 = __builtin_bit_cast(h2, xv.w);
#if __has_builtin(__builtin_amdgcn_fdot2)
    float acc = __builtin_amdgcn_fdot2(w0, x0, 0.f, false);
    acc = __builtin_amdgcn_fdot2(w1, x1, acc, false);
    acc = __builtin_amdgcn_fdot2(w2, x2, acc, false);
    acc = __builtin_amdgcn_fdot2(w3, x3, acc, false);
    return acc;
#else
    float acc = (float)w0.x*(float)x0.x + (float)w0.y*(float)x0.y
              + (float)w1.x*(float)x1.x + (float)w1.y*(float)x1.y
              + (float)w2.x*(float)x2.x + (float)w2.y*(float)x2.y
              + (float)w3.x*(float)x3.x + (float)w3.y*(float)x3.y;
    return acc;
#endif
}

// ---------------- k_prep: W -> fp16 (2 layouts), x-patch gather -> fp16 ----
__global__ __launch_bounds__(256) void k_prep(
    const float* __restrict__ pose, const float* __restrict__ W,
    uint4* __restrict__ Wh, uint4* __restrict__ xh, uint4* __restrict__ Wg)
{
    const int t  = threadIdx.x;
    const int bx = blockIdx.x;
    if (bx < NSITES) {
        const int site = bx;
        const int b = site / LSZ;
        const int l = site - b * LSZ;
        const int oh = l / HWD, ow = l - oh * HWD;
        for (int kk = t; kk < KKA_; kk += 256) {
            const int p = kk >> 5, a = kk & 31;
            const int ky = p / 3 - 1, kx = p % 3 - 1;
            const int y = oh + ky, x = ow + kx;
            const bool inb = (y >= 0 && y < HWD && x >= 0 && x < HWD);
            const float* pp = pose + ((size_t)b * 256 + a * 8) * LSZ
                            + (inb ? (y * HWD + x) : 0);
            uint32_t uo[4];
            #pragma unroll
            for (int cp = 0; cp < 4; ++cp) {
                const float f0 = inb ? pp[(2*cp)   * LSZ] : 0.f;
                const float f1 = inb ? pp[(2*cp+1) * LSZ] : 0.f;
                h2 hh; hh.x = (_Float16)f0; hh.y = (_Float16)f1;
                uo[cp] = __builtin_bit_cast(uint32_t, hh);
            }
            uint4 o; o.x = uo[0]; o.y = uo[1]; o.z = uo[2]; o.w = uo[3];
            xh[(size_t)site * KKA_ + kk] = o;
        }
    } else {
        const int wb = bx - NSITES;
        const int kk = wb * 4 + (t >> 6);
        const int ln = t & 63;
        const float* Wr = W + (size_t)kk * (BD_ * 8);
        #pragma unroll
        for (int u = 0; u < 8; ++u) {
            const int p = ln * 8 + u;
            const float4 fa = *(const float4*)(Wr + p * 8);
            const float4 fb = *(const float4*)(Wr + p * 8 + 4);
            uint32_t uo[4];
            h2 h0; h0.x=(_Float16)fa.x; h0.y=(_Float16)fa.y; uo[0]=__builtin_bit_cast(uint32_t,h0);
            h2 h1; h1.x=(_Float16)fa.z; h1.y=(_Float16)fa.w; uo[1]=__builtin_bit_cast(uint32_t,h1);
            h2 hv; hv.x=(_Float16)fb.x; hv.y=(_Float16)fb.y; uo[2]=__builtin_bit_cast(uint32_t,hv);
            h2 h3; h3.x=(_Float16)fb.z; h3.y=(_Float16)fb.w; uo[3]=__builtin_bit_cast(uint32_t,h3);
            uint4 o; o.x=uo[0]; o.y=uo[1]; o.z=uo[2]; o.w=uo[3];
            Wh[(size_t)kk * 512 + u * 64 + ln] = o;   // sweep layout (coalesced)
            Wg[(size_t)kk * 512 + p] = o;             // gemm B layout [kk][p][c]
        }
    }
}

// ---------------- k_gemm1: s1 = x @ W, K-split 8-way, XCD-pinned -----------
// R22: kc = bid & 7 -> each XCD (dispatch round-robin %8) sees ONE k-chunk:
// per-XCD working set = B 288KB + A 602KB << 4MB L2. 9 MFMAs/block.
__global__ __launch_bounds__(256) void k_gemm1(
    const uint4* __restrict__ xh, const uint4* __restrict__ Wg,
    float* __restrict__ gp)
{
    const int bid = blockIdx.x;
    const int kc  = bid & 7;                 // XCD-pinned chunk
    const int r2  = bid >> 3;                // 0..391
    const int nb  = r2 & 7;
    const int mb  = r2 >> 3;                 // 0..48
    const int t   = threadIdx.x;
    const int w   = t >> 6;                  // 0..3
    const int l   = t & 63;
    const int m0  = mb * 16;
    const int n0  = nb * 64 + w * 16;
    const int row = l & 15;
    const int sub = l >> 4;                  // 0..3

    f4 acc = {0.f, 0.f, 0.f, 0.f};
    const uint4* ap = xh + (size_t)(m0 + row) * KKA_ + kc * 36 + sub;
    const uint4* bp = Wg + ((size_t)kc * 36 + sub) * 512 + (n0 + row);

    #pragma unroll
    for (int ks = 0; ks < 9; ++ks) {
        const h8 a = __builtin_bit_cast(h8, ap[ks * 4]);
        const h8 b = __builtin_bit_cast(h8, bp[(size_t)ks * 4 * 512]);
        acc = __builtin_amdgcn_mfma_f32_16x16x32_f16(a, b, acc, 0, 0, 0);
    }

    float* op = gp + (size_t)kc * (NSITES * BD_)
              + (size_t)(m0 + sub * 4) * BD_ + n0 + row;
    op[0]        = acc[0];
    op[BD_]      = acc[1];
    op[2 * BD_]  = acc[2];
    op[3 * BD_]  = acc[3];
}

// ---------------- k_red1: v1 = squash(sum_kc gp / 32) -> vbuf --------------
__global__ __launch_bounds__(256) void k_red1(
    const float* __restrict__ gp, float* __restrict__ vbuf)
{
    const int site = blockIdx.x * 4 + (threadIdx.x >> 6);
    const int ln = threadIdx.x & 63;
    float tv[8] = {0.f,0.f,0.f,0.f,0.f,0.f,0.f,0.f};
    #pragma unroll
    for (int kc = 0; kc < KC; ++kc) {
        const float4* sp = (const float4*)(gp + (size_t)kc * (NSITES * BD_)
                                           + (size_t)site * BD_ + ln * 8);
        const float4 a = sp[0], b = sp[1];
        tv[0]+=a.x; tv[1]+=a.y; tv[2]+=a.z; tv[3]+=a.w;
        tv[4]+=b.x; tv[5]+=b.y; tv[6]+=b.z; tv[7]+=b.w;
    }
    float msq = 0.f;
    #pragma unroll
    for (int j = 0; j < 8; ++j) { tv[j] *= (1.f / 32.f); msq += tv[j] * tv[j]; }
    msq += __shfl_xor(msq, 1, 64);
    const float fac = sqrtf(msq) / (1.f + msq);
    #pragma unroll
    for (int j = 0; j < 8; ++j) vbuf[(size_t)site * BD_ + ln * 8 + j] = tv[j] * fac;
}

// ---------------- k_sweep<PASS>: routing sweep, XCD-pinned rg --------------
// R22: 1-D grid, rg = bid & 7 (8 rgs of 36 rows), sg = bid >> 3. With %8
// round-robin dispatch, XCD k sees only rg=k: per-XCD working set = W-slice
// 288KB + x-slice 451KB << 4MB L2 -> W served from L2, not L3 (the ~10 TB/s
// L3 wall explains R6..R21's config-invariant ~46us sweeps).
template<int PASS>
__global__ __launch_bounds__(384, 4) void k_sweep(
    const uint4* __restrict__ Wh, const uint4* __restrict__ xh,
    const float* __restrict__ vbuf, float* __restrict__ partial)
{
    const int bid = blockIdx.x;
    const int rg  = bid & 7;
    const int sg  = bid >> 3;
    const int t  = threadIdx.x;
    const int w  = t >> 6;           // 0..5
    const int ln = t & 63;
    const int site0 = sg * SITES_PER_BLK;
    const int kk0 = __builtin_amdgcn_readfirstlane(rg * ROWS_PER_BLK + w);

    float v[SITES_PER_BLK][8];
    #pragma unroll
    for (int s = 0; s < SITES_PER_BLK; ++s) {
        const float4* vp = (const float4*)(vbuf + (size_t)(site0 + s) * BD_ + ln * 8);
        const float4 a = vp[0], bq = vp[1];
        v[s][0]=a.x;  v[s][1]=a.y;  v[s][2]=a.z;  v[s][3]=a.w;
        v[s][4]=bq.x; v[s][5]=bq.y; v[s][6]=bq.z; v[s][7]=bq.w;
        PIN8(v[s]);
    }

    float sacc[SITES_PER_BLK][8];
    #pragma unroll
    for (int s = 0; s < SITES_PER_BLK; ++s)
        #pragma unroll
        for (int j = 0; j < 8; ++j) sacc[s][j] = 0.f;

    const uint4* Wrow = Wh + (size_t)kk0 * 512;   // uniform base (SGPR)
    const uint4* xrow = xh + kk0;

    #pragma unroll 1
    for (int r = 0; r < ROWS_PER_WAVE; ++r) {
        uint4 wr[8];
        #pragma unroll
        for (int u = 0; u < 8; ++u) wr[u] = Wrow[u * 64 + ln];  // 1KB coalesced
        Wrow += NW * 512;

        #pragma unroll
        for (int s = 0; s < SITES_PER_BLK; ++s) {
            const uint4 xr = xrow[(size_t)(site0 + s) * KKA_];  // uniform -> s_load
            float po[8];
            #pragma unroll
            for (int j = 0; j < 8; ++j) po[j] = dot8(wr[j], xr);
            float up = v[s][0] * po[0];
            #pragma unroll
            for (int j = 1; j < 8; ++j) up += v[s][j] * po[j];
            up += __shfl_xor(up, 1, 64);          // full D=16 dot
            const float e = __expf(up);           // logits bounded, no max
            float se = e;
            se += __shfl_xor(se, 2, 64);
            se += __shfl_xor(se, 4, 64);
            se += __shfl_xor(se, 8, 64);
            se += __shfl_xor(se, 16, 64);
            se += __shfl_xor(se, 32, 64);
            const float c = e * __builtin_amdgcn_rcpf(se);
            #pragma unroll
            for (int j = 0; j < 8; ++j) sacc[s][j] += c * po[j];
        }
        xrow += NW;
    }

    // cross-wave reduce -> partial[site][rg][p]
    __shared__ float red[NW * BD_];   // 12 KB
    #pragma unroll
    for (int s = 0; s < SITES_PER_BLK; ++s) {
        if (s) __syncthreads();
        float4 r0, r1;
        r0.x=sacc[s][0]; r0.y=sacc[s][1]; r0.z=sacc[s][2]; r0.w=sacc[s][3];
        r1.x=sacc[s][4]; r1.y=sacc[s][5]; r1.z=sacc[s][6]; r1.w=sacc[s][7];
        *(float4*)&red[w * BD_ + ln * 8]     = r0;
        *(float4*)&red[w * BD_ + ln * 8 + 4] = r1;
        __syncthreads();
        for (int p = t; p < BD_; p += 384) {
            float acc = red[p];
            #pragma unroll
            for (int ww = 1; ww < NW; ++ww) acc += red[ww * BD_ + p];
            partial[((size_t)(site0 + s) * NRG + rg) * BD_ + p] = acc;
        }
    }
}

// ---------------- k_reduce<PASS>: sum partials, squash (2: v+=, 3: out) ----
template<int PASS>
__global__ __launch_bounds__(256) void k_reduce(
    const float* __restrict__ partial, float* __restrict__ vbuf,
    float* __restrict__ out)
{
    const int site = blockIdx.x * 4 + (threadIdx.x >> 6);
    const int ln = threadIdx.x & 63;
    float tv[8] = {0.f,0.f,0.f,0.f,0.f,0.f,0.f,0.f};
    #pragma unroll
    for (int rg = 0; rg < NRG; ++rg) {
        const float4* pp4 = (const float4*)(partial + ((size_t)site * NRG + rg) * BD_ + ln * 8);
        const float4 a = pp4[0], b = pp4[1];
        tv[0]+=a.x; tv[1]+=a.y; tv[2]+=a.z; tv[3]+=a.w;
        tv[4]+=b.x; tv[5]+=b.y; tv[6]+=b.z; tv[7]+=b.w;
    }
    float msq = 0.f;
    #pragma unroll
    for (int j = 0; j < 8; ++j) msq += tv[j] * tv[j];
    msq += __shfl_xor(msq, 1, 64);                 // partner holds other 8 d's
    const float fac = sqrtf(msq) / (1.f + msq);    // squash factor
    if (PASS == 2) {
        #pragma unroll
        for (int j = 0; j < 8; ++j) vbuf[(size_t)site * BD_ + ln * 8 + j] += tv[j] * fac;  // v12
    } else {
        const int b = site / LSZ;
        const int l = site - b * LSZ;
        float* op = out + (size_t)b * BD_ * LSZ + l;
        #pragma unroll
        for (int j = 0; j < 8; ++j) op[(size_t)(ln * 8 + j) * LSZ] = tv[j] * fac;
    }
}

extern "C" void kernel_launch(void* const* d_in, const int* in_sizes, int n_in,
                              void* d_out, int out_size, void* d_ws, size_t ws_size,
                              hipStream_t stream) {
    const float* pose = (const float*)d_in[0];
    const float* W    = (const float*)d_in[1];
    float* out        = (float*)d_out;

    if (ws_size < (size_t)WS_NEED) return;

    uint8_t* ws = (uint8_t*)d_ws;
    uint4*  Wh     = (uint4*)  (ws + WH_OFF);
    uint4*  xh     = (uint4*)  (ws + XH_OFF);
    uint4*  Wg     = (uint4*)  (ws + WG_OFF);
    float*  gp     = (float*)  (ws + GP_OFF);
    float* partial = (float*)  (ws + PART_OFF);
    float* vbuf    = (float*)  (ws + VBUF_OFF);

    k_prep<<<dim3(NSITES + 72), dim3(256), 0, stream>>>(pose, W, Wh, xh, Wg);

    // pass 1: MFMA GEMM, K-split 8-way, kc XCD-pinned via bid&7
    k_gemm1<<<dim3(49 * 8 * KC), dim3(256), 0, stream>>>(xh, Wg, gp);
    k_red1<<<dim3(NSITES / 4), dim3(256), 0, stream>>>(gp, vbuf);

    const dim3 gs(196 * NRG);   // 1-D: rg = bid & 7 (XCD-pinned), sg = bid >> 3
    k_sweep<2><<<gs, dim3(384), 0, stream>>>(Wh, xh, vbuf, partial);
    k_reduce<2><<<dim3(NSITES / 4), dim3(256), 0, stream>>>(partial, vbuf, out);
    k_sweep<3><<<gs, dim3(384), 0, stream>>>(Wh, xh, vbuf, partial);
    k_reduce<3><<<dim3(NSITES / 4), dim3(256), 0, stream>>>(partial, vbuf, out);
}

// Round 25
// 170.648 us; speedup vs baseline: 1.1951x; 1.1951x over previous
//
#include <hip/hip_runtime.h>
#include <stdint.h>

// Problem constants
#define NSITES 784          // 4 * 196
#define LSZ    196          // 14*14
#define HWD    14
#define KKA_   288
#define BD_    512
#define NRG    6            // row-groups (288/48)
#define ROWS_PER_BLK 48
#define NW     8            // waves per block
#define ROWS_PER_WAVE 6     // 48 / 8 waves
#define SITES_PER_BLK 4
#define KC     6            // gemm1 K-split chunks (2304/384)

// workspace layout (bytes) — R21 layout
#define WH_OFF    0            // W fp16 transposed (sweeps): 2,359,296
#define XH_OFF    2359296      // x fp16 [site][kk][c]:       3,612,672
#define WG_OFF    5971968      // W fp16 [kk][p][c] (gemm B): 2,359,296
#define PART_OFF  9936896      // partial: 784*6*512*4      = 9,633,792
#define VBUF_OFF  19570688     // v: 784*512*4              = 1,605,632
#define WS_NEED   21176320

typedef _Float16 h2 __attribute__((ext_vector_type(2)));
typedef _Float16 h8 __attribute__((ext_vector_type(8)));
typedef float    f4 __attribute__((ext_vector_type(4)));

// keep 8 floats pinned in VGPRs
#define PIN8(p) asm volatile("" : "+v"(p[0]),"+v"(p[1]),"+v"(p[2]),"+v"(p[3]), \
                                  "+v"(p[4]),"+v"(p[5]),"+v"(p[6]),"+v"(p[7]))

// 8-term fp16 dot with fp32 accumulate
__device__ __forceinline__ float dot8(const uint4 wv, const uint4 xv) {
    h2 w0 = __builtin_bit_cast(h2, wv.x), w1 = __builtin_bit_cast(h2, wv.y),
       w2 = __builtin_bit_cast(h2, wv.z), w3 = __builtin_bit_cast(h2, wv.w);
    h2 x0 = __builtin_bit_cast(h2, xv.x), x1 = __builtin_bit_cast(h2, xv.y),
       x2 = __builtin_bit_cast(h2, xv.z), x3 = __builtin_bit_cast(h2, xv.w);
#if __has_builtin(__builtin_amdgcn_fdot2)
    float acc = __builtin_amdgcn_fdot2(w0, x0, 0.f, false);
    acc = __builtin_amdgcn_fdot2(w1, x1, acc, false);
    acc = __builtin_amdgcn_fdot2(w2, x2, acc, false);
    acc = __builtin_amdgcn_fdot2(w3, x3, acc, false);
    return acc;
#else
    float acc = (float)w0.x*(float)x0.x + (float)w0.y*(float)x0.y
              + (float)w1.x*(float)x1.x + (float)w1.y*(float)x1.y
              + (float)w2.x*(float)x2.x + (float)w2.y*(float)x2.y
              + (float)w3.x*(float)x3.x + (float)w3.y*(float)x3.y;
    return acc;
#endif
}

// ---------------- k_prep: x-gather (coalesced) + W -> fp16 (2 layouts) -----
// R25: x-gather re-axed — block per (b,kk), lanes sweep l. Since
// y*14+x = l + (ky*14+kx), consecutive lanes read CONSECUTIVE pose addresses
// (old version: 8 scalar loads @ 784B stride per thread, fully uncoalesced).
// Writes are scattered 16B but fire-and-forget.
__global__ __launch_bounds__(256) void k_prep(
    const float* __restrict__ pose, const float* __restrict__ W,
    uint4* __restrict__ Wh, uint4* __restrict__ xh, uint4* __restrict__ Wg)
{
    const int t  = threadIdx.x;
    const int bx = blockIdx.x;
    if (bx < 4 * KKA_) {                     // x-gather: (b, kk)
        const int b  = bx / KKA_;
        const int kk = bx - b * KKA_;
        const int p  = kk >> 5, a = kk & 31;
        const int ky = p / 3 - 1, kx = p % 3 - 1;
        if (t < LSZ) {
            const int l  = t;
            const int oh = l / HWD, ow = l - oh * HWD;
            const int y = oh + ky, x = ow + kx;
            const bool inb = (y >= 0 && y < HWD && x >= 0 && x < HWD);
            const float* pp = pose + ((size_t)b * 256 + a * 8) * LSZ
                            + (inb ? (y * HWD + x) : 0);
            uint32_t uo[4];
            #pragma unroll
            for (int cp = 0; cp < 4; ++cp) {
                const float f0 = inb ? pp[(2*cp)   * LSZ] : 0.f;   // coalesced over l
                const float f1 = inb ? pp[(2*cp+1) * LSZ] : 0.f;
                h2 hh; hh.x = (_Float16)f0; hh.y = (_Float16)f1;
                uo[cp] = __builtin_bit_cast(uint32_t, hh);
            }
            uint4 o; o.x = uo[0]; o.y = uo[1]; o.z = uo[2]; o.w = uo[3];
            xh[((size_t)b * LSZ + l) * KKA_ + kk] = o;
        }
    } else {                                 // W convert: 4 kk per block
        const int wb = bx - 4 * KKA_;
        const int kk = wb * 4 + (t >> 6);
        const int ln = t & 63;
        const float* Wr = W + (size_t)kk * (BD_ * 8);
        #pragma unroll
        for (int u = 0; u < 8; ++u) {
            const int p = ln * 8 + u;
            const float4 fa = *(const float4*)(Wr + p * 8);
            const float4 fb = *(const float4*)(Wr + p * 8 + 4);
            uint32_t uo[4];
            h2 h0; h0.x=(_Float16)fa.x; h0.y=(_Float16)fa.y; uo[0]=__builtin_bit_cast(uint32_t,h0);
            h2 h1; h1.x=(_Float16)fa.z; h1.y=(_Float16)fa.w; uo[1]=__builtin_bit_cast(uint32_t,h1);
            h2 hv; hv.x=(_Float16)fb.x; hv.y=(_Float16)fb.y; uo[2]=__builtin_bit_cast(uint32_t,hv);
            h2 h3; h3.x=(_Float16)fb.z; h3.y=(_Float16)fb.w; uo[3]=__builtin_bit_cast(uint32_t,h3);
            uint4 o; o.x=uo[0]; o.y=uo[1]; o.z=uo[2]; o.w=uo[3];
            Wh[(size_t)kk * 512 + u * 64 + ln] = o;   // sweep layout (coalesced)
            Wg[(size_t)kk * 512 + p] = o;             // gemm B layout [kk][p][c]
        }
    }
}

// ---------------- k_gemm1: s1 = x @ W, K-split, LDS-staged A ---------------
// R25: A-tile (16 sites x 48 uint4 = 12.5KB padded) staged cooperatively in
// LDS (coalesced, 3 loads/thread) instead of per-lane 64-way scattered
// global loads per MFMA (R20/R21's ~40us disease). B stays global (L2-hot,
// semi-coalesced). Grid (49,8,6) as R21.
__global__ __launch_bounds__(256) void k_gemm1(
    const uint4* __restrict__ xh, const uint4* __restrict__ Wg,
    float* __restrict__ gp)
{
    const int t   = threadIdx.x;
    const int w   = t >> 6;                  // 0..3
    const int l   = t & 63;
    const int m0  = blockIdx.x * 16;
    const int n0  = blockIdx.y * 64 + w * 16;
    const int kc  = blockIdx.z;              // 0..5
    const int row = l & 15;
    const int sub = l >> 4;                  // 0..3

    __shared__ uint4 x_lds[16][49];          // +1 pad (bank spread)
    #pragma unroll
    for (int q = 0; q < 3; ++q) {
        const int idx = t + 256 * q;         // 0..767 = 16*48
        const int r = idx / 48, i = idx - r * 48;
        x_lds[r][i] = xh[(size_t)(m0 + r) * KKA_ + kc * 48 + i];  // coalesced
    }
    __syncthreads();

    f4 acc = {0.f, 0.f, 0.f, 0.f};
    const uint4* bp = Wg + ((size_t)kc * 48 + sub) * 512 + (n0 + row);

    #pragma unroll
    for (int ks = 0; ks < 12; ++ks) {
        const h8 a = __builtin_bit_cast(h8, x_lds[row][sub + ks * 4]);
        const h8 b = __builtin_bit_cast(h8, bp[(size_t)ks * 4 * 512]);
        acc = __builtin_amdgcn_mfma_f32_16x16x32_f16(a, b, acc, 0, 0, 0);
    }

    float* op = gp + (size_t)kc * (NSITES * BD_)
              + (size_t)(m0 + sub * 4) * BD_ + n0 + row;
    op[0]        = acc[0];
    op[BD_]      = acc[1];
    op[2 * BD_]  = acc[2];
    op[3 * BD_]  = acc[3];
}

// ---------------- k_red1: v1 = squash(sum_kc gp / 32) -> vbuf --------------
__global__ __launch_bounds__(256) void k_red1(
    const float* __restrict__ gp, float* __restrict__ vbuf)
{
    const int site = blockIdx.x * 4 + (threadIdx.x >> 6);
    const int ln = threadIdx.x & 63;
    float tv[8] = {0.f,0.f,0.f,0.f,0.f,0.f,0.f,0.f};
    #pragma unroll
    for (int kc = 0; kc < KC; ++kc) {
        const float4* sp = (const float4*)(gp + (size_t)kc * (NSITES * BD_)
                                           + (size_t)site * BD_ + ln * 8);
        const float4 a = sp[0], b = sp[1];
        tv[0]+=a.x; tv[1]+=a.y; tv[2]+=a.z; tv[3]+=a.w;
        tv[4]+=b.x; tv[5]+=b.y; tv[6]+=b.z; tv[7]+=b.w;
    }
    float msq = 0.f;
    #pragma unroll
    for (int j = 0; j < 8; ++j) { tv[j] *= (1.f / 32.f); msq += tv[j] * tv[j]; }
    msq += __shfl_xor(msq, 1, 64);
    const float fac = sqrtf(msq) / (1.f + msq);
    #pragma unroll
    for (int j = 0; j < 8; ++j) vbuf[(size_t)site * BD_ + ln * 8 + j] = tv[j] * fac;
}

// ---------------- k_sweep<PASS>: routing sweep (passes 2,3) — R21 form -----
template<int PASS>
__global__ __launch_bounds__(512, 4) void k_sweep(
    const uint4* __restrict__ Wh, const uint4* __restrict__ xh,
    const float* __restrict__ vbuf, float* __restrict__ partial)
{
    const int t  = threadIdx.x;
    const int w  = t >> 6;           // 0..7
    const int ln = t & 63;
    const int sg = blockIdx.x;
    const int rg = blockIdx.y;
    const int site0 = sg * SITES_PER_BLK;
    const int kk0 = __builtin_amdgcn_readfirstlane(rg * ROWS_PER_BLK + w);

    float v[SITES_PER_BLK][8];
    #pragma unroll
    for (int s = 0; s < SITES_PER_BLK; ++s) {
        const float4* vp = (const float4*)(vbuf + (size_t)(site0 + s) * BD_ + ln * 8);
        const float4 a = vp[0], bq = vp[1];
        v[s][0]=a.x;  v[s][1]=a.y;  v[s][2]=a.z;  v[s][3]=a.w;
        v[s][4]=bq.x; v[s][5]=bq.y; v[s][6]=bq.z; v[s][7]=bq.w;
        PIN8(v[s]);
    }

    float sacc[SITES_PER_BLK][8];
    #pragma unroll
    for (int s = 0; s < SITES_PER_BLK; ++s)
        #pragma unroll
        for (int j = 0; j < 8; ++j) sacc[s][j] = 0.f;

    const uint4* Wrow = Wh + (size_t)kk0 * 512;   // uniform base (SGPR)
    const uint4* xrow = xh + kk0;

    #pragma unroll 1
    for (int r = 0; r < ROWS_PER_WAVE; ++r) {
        uint4 wr[8];
        #pragma unroll
        for (int u = 0; u < 8; ++u) wr[u] = Wrow[u * 64 + ln];  // 1KB coalesced
        Wrow += NW * 512;

        #pragma unroll
        for (int s = 0; s < SITES_PER_BLK; ++s) {
            const uint4 xr = xrow[(size_t)(site0 + s) * KKA_];  // uniform -> s_load
            float po[8];
            #pragma unroll
            for (int j = 0; j < 8; ++j) po[j] = dot8(wr[j], xr);
            float up = v[s][0] * po[0];
            #pragma unroll
            for (int j = 1; j < 8; ++j) up += v[s][j] * po[j];
            up += __shfl_xor(up, 1, 64);          // full D=16 dot
            const float e = __expf(up);           // logits bounded, no max
            float se = e;
            se += __shfl_xor(se, 2, 64);
            se += __shfl_xor(se, 4, 64);
            se += __shfl_xor(se, 8, 64);
            se += __shfl_xor(se, 16, 64);
            se += __shfl_xor(se, 32, 64);
            const float c = e * __builtin_amdgcn_rcpf(se);
            #pragma unroll
            for (int j = 0; j < 8; ++j) sacc[s][j] += c * po[j];
        }
        xrow += NW;
    }

    // cross-wave reduce -> partial[site][rg][p]
    __shared__ float red[NW * BD_];   // 16 KB
    #pragma unroll
    for (int s = 0; s < SITES_PER_BLK; ++s) {
        if (s) __syncthreads();
        float4 r0, r1;
        r0.x=sacc[s][0]; r0.y=sacc[s][1]; r0.z=sacc[s][2]; r0.w=sacc[s][3];
        r1.x=sacc[s][4]; r1.y=sacc[s][5]; r1.z=sacc[s][6]; r1.w=sacc[s][7];
        *(float4*)&red[w * BD_ + ln * 8]     = r0;
        *(float4*)&red[w * BD_ + ln * 8 + 4] = r1;
        __syncthreads();
        {
            const int p = t;          // 512 threads = 512 p values
            float acc = red[p];
            #pragma unroll
            for (int ww = 1; ww < NW; ++ww) acc += red[ww * BD_ + p];
            partial[((size_t)(site0 + s) * NRG + rg) * BD_ + p] = acc;
        }
    }
}

// ---------------- k_reduce<PASS>: sum partials, squash (2: v+=, 3: out) ----
template<int PASS>
__global__ __launch_bounds__(256) void k_reduce(
    const float* __restrict__ partial, float* __restrict__ vbuf,
    float* __restrict__ out)
{
    const int site = blockIdx.x * 4 + (threadIdx.x >> 6);
    const int ln = threadIdx.x & 63;
    float tv[8] = {0.f,0.f,0.f,0.f,0.f,0.f,0.f,0.f};
    #pragma unroll
    for (int rg = 0; rg < NRG; ++rg) {
        const float4* pp4 = (const float4*)(partial + ((size_t)site * NRG + rg) * BD_ + ln * 8);
        const float4 a = pp4[0], b = pp4[1];
        tv[0]+=a.x; tv[1]+=a.y; tv[2]+=a.z; tv[3]+=a.w;
        tv[4]+=b.x; tv[5]+=b.y; tv[6]+=b.z; tv[7]+=b.w;
    }
    float msq = 0.f;
    #pragma unroll
    for (int j = 0; j < 8; ++j) msq += tv[j] * tv[j];
    msq += __shfl_xor(msq, 1, 64);                 // partner holds other 8 d's
    const float fac = sqrtf(msq) / (1.f + msq);    // squash factor
    if (PASS == 2) {
        #pragma unroll
        for (int j = 0; j < 8; ++j) vbuf[(size_t)site * BD_ + ln * 8 + j] += tv[j] * fac;  // v12
    } else {
        const int b = site / LSZ;
        const int l = site - b * LSZ;
        float* op = out + (size_t)b * BD_ * LSZ + l;
        #pragma unroll
        for (int j = 0; j < 8; ++j) op[(size_t)(ln * 8 + j) * LSZ] = tv[j] * fac;
    }
}

extern "C" void kernel_launch(void* const* d_in, const int* in_sizes, int n_in,
                              void* d_out, int out_size, void* d_ws, size_t ws_size,
                              hipStream_t stream) {
    const float* pose = (const float*)d_in[0];
    const float* W    = (const float*)d_in[1];
    float* out        = (float*)d_out;

    if (ws_size < (size_t)WS_NEED) return;

    uint8_t* ws = (uint8_t*)d_ws;
    uint4*  Wh     = (uint4*)  (ws + WH_OFF);
    uint4*  xh     = (uint4*)  (ws + XH_OFF);
    uint4*  Wg     = (uint4*)  (ws + WG_OFF);
    float* partial = (float*)  (ws + PART_OFF);
    float* vbuf    = (float*)  (ws + VBUF_OFF);

    k_prep<<<dim3(4 * KKA_ + 72), dim3(256), 0, stream>>>(pose, W, Wh, xh, Wg);

    // pass 1: MFMA GEMM, K-split 6-way, LDS-staged A
    k_gemm1<<<dim3(49, 8, KC), dim3(256), 0, stream>>>(xh, Wg, partial);
    k_red1<<<dim3(NSITES / 4), dim3(256), 0, stream>>>(partial, vbuf);

    const dim3 gs(NSITES / SITES_PER_BLK, NRG);   // (196, 6)
    k_sweep<2><<<gs, dim3(512), 0, stream>>>(Wh, xh, vbuf, partial);
    k_reduce<2><<<dim3(NSITES / 4), dim3(256), 0, stream>>>(partial, vbuf, out);
    k_sweep<3><<<gs, dim3(512), 0, stream>>>(Wh, xh, vbuf, partial);
    k_reduce<3><<<dim3(NSITES / 4), dim3(256), 0, stream>>>(partial, vbuf, out);
}